// Round 10
// baseline (405.897 us; speedup 1.0000x reference)
//
#include <hip/hip_runtime.h>

#define NB 64
#define NM 128
#define NAI 75
#define NPI 14
#define NH 50
#define NAO 50
#define NPO 50

typedef __attribute__((ext_vector_type(8))) short s8v;
typedef __attribute__((ext_vector_type(4))) float f4v;

union ABfrag { s8v v; unsigned short u[8]; unsigned w[4]; };

__device__ __forceinline__ unsigned short f2bf(float x) {
    union { float f; unsigned u; } c{x};
    unsigned r = c.u + 0x7fffu + ((c.u >> 16) & 1u);
    return (unsigned short)(r >> 16);
}
__device__ __forceinline__ float bf2f(unsigned short b) {
    union { unsigned u; float f; } c{(unsigned)b << 16};
    return c.f;
}

// t[bi][h] = atom[bi,:] @ (W_AP[:75]+W_AP[75:]), bf16, rows padded to 64
__global__ void k_t(const float* __restrict__ atom, const float* __restrict__ W_AP,
                    unsigned short* __restrict__ t) {
    int idx = blockIdx.x * 256 + threadIdx.x;
    if (idx >= NB * NM * 64) return;
    int bi = idx >> 6, h = idx & 63;
    unsigned short v = 0;
    if (h < NH) {
        const float* ar = atom + bi * NAI;
        float acc = 0.f;
#pragma unroll
        for (int f = 0; f < NAI; ++f)
            acc = fmaf(ar[f], W_AP[f * NH + h] + W_AP[(f + NAI) * NH + h], acc);
        v = f2bf(acc);
    }
    t[idx] = v;
}

// W_P^T bf16: wt[o][k], o<64, k<128. k<64 -> W_P[k][o] (AP, k<50); k>=64 -> W_P[50+(k-64)][o] (PP).
__global__ void k_prep(const float* __restrict__ W_P, unsigned short* __restrict__ wt) {
    int idx = blockIdx.x * 256 + threadIdx.x;
    if (idx >= 64 * 128) return;
    int o = idx >> 7, k = idx & 127;
    float v = 0.f;
    if (o < NPO) {
        if (k < 64) { if (k < NH) v = W_P[k * NPO + o]; }
        else        { if (k - 64 < NH) v = W_P[(NH + k - 64) * NPO + o]; }
    }
    wt[idx] = f2bf(v);
}

__global__ __launch_bounds__(256, 4) void k_main(
    const float* __restrict__ atom, const float* __restrict__ pair,
    const float* __restrict__ amask, const float* __restrict__ pmask,
    const float* __restrict__ W_AA, const float* __restrict__ b_AA,
    const float* __restrict__ W_PA, const float* __restrict__ b_PA,
    const float* __restrict__ W_A,  const float* __restrict__ b_A,
    const float* __restrict__ b_AP,
    const float* __restrict__ W_PP, const float* __restrict__ b_PP,
    const float* __restrict__ b_P,
    const unsigned short* __restrict__ t_ws, const unsigned short* __restrict__ wt_ws,
    float* __restrict__ outA, float* __restrict__ outP)
{
    // XOR-swizzled (T2-style, 16B granular) unpadded tiles: kills the 2.6M bank conflicts
    // AND drops LDS below 40KB -> 4 blocks/CU (was 3).
    __shared__ __align__(16) unsigned short t_lds[NM * 64];    // 16 KB, row=128B, swz
    __shared__ __align__(16) unsigned short wt_lds[64 * 128];  // 16 KB, row=256B, swz
    __shared__ __align__(16) float wpp_lds[NPI * 64];          // 3.5 KB (broadcast reads)
    __shared__ __align__(16) float pm_lds[NM];
    __shared__ float bP_lds[64], bPP_lds[64], bAP_lds[64];
    __shared__ float atom_lds[NAI];
    __shared__ float wred[4][NPI];
    __shared__ float S_lds[NPI];
    __shared__ float conc[2 * NH];

    const int tid  = threadIdx.x;
    const int b    = blockIdx.x >> 7;
    const int i    = blockIdx.x & 127;
    const int wave = tid >> 6;
    const int lane = tid & 63;
    const int ln   = lane & 15;
    const int hi   = lane >> 4;          // 0..3

    // ---------------- stage ----------------
    {   // t tile: 1024 x 16B chunks; row = c>>3; swizzle byte-bits 4..6 by row&7
        const float4* src = (const float4*)(t_ws + (size_t)b * NM * 64);
        for (int c = tid; c < 1024; c += 256) {
            float4 v = src[c];
            *(float4*)((char*)t_lds + ((c * 16) ^ (((c >> 3) & 7) << 4))) = v;
        }
    }
    {   // wt tile: 1024 x 16B chunks; row = c>>4
        const float4* src = (const float4*)wt_ws;
        for (int c = tid; c < 1024; c += 256) {
            float4 v = src[c];
            *(float4*)((char*)wt_lds + ((c * 16) ^ (((c >> 4) & 7) << 4))) = v;
        }
    }
    for (int x = tid; x < NPI * 64; x += 256) {
        int f = x >> 6, h = x & 63;
        wpp_lds[x] = (h < NH) ? W_PP[f * NH + h] : 0.f;
    }
    if (tid < 32) ((float4*)pm_lds)[tid] = ((const float4*)(pmask + (size_t)blockIdx.x * NM))[tid];
    if (tid < 64) {
        bP_lds[tid]  = (tid < NPO) ? b_P[tid]  : 0.f;
        bPP_lds[tid] = (tid < NH)  ? b_PP[tid] : 0.f;
        bAP_lds[tid] = (tid < NH)  ? b_AP[tid] : 0.f;
    }
    if (tid >= 64 && tid < 64 + NAI) atom_lds[tid - 64] = atom[(size_t)blockIdx.x * NAI + (tid - 64)];
    __syncthreads();

    // ---------------- pair rows straight from global (float2; L1 dedups hi-redundancy) ----
    const int j0 = wave * 32 + ln;
    const int j1 = j0 + 16;
    float pr0[NPI], pr1[NPI];
    {
        const float2* q0 = (const float2*)(pair + ((size_t)blockIdx.x * NM + j0) * NPI);
        const float2* q1 = (const float2*)(pair + ((size_t)blockIdx.x * NM + j1) * NPI);
#pragma unroll
        for (int f2 = 0; f2 < NPI / 2; ++f2) {
            float2 a = q0[f2], c = q1[f2];
            pr0[2 * f2] = a.x; pr0[2 * f2 + 1] = a.y;
            pr1[2 * f2] = c.x; pr1[2 * f2 + 1] = c.y;
        }
    }

    f4v acc[2][4];
#pragma unroll
    for (int m = 0; m < 2; ++m)
#pragma unroll
        for (int n = 0; n < 4; ++n) acc[m][n] = f4v{0.f, 0.f, 0.f, 0.f};

#pragma unroll
    for (int ks = 0; ks < 4; ++ks) {
        // B frags: lane holds W[k = ks*32+8hi+e][o = n*16+ln]
        s8v bfr[4];
#pragma unroll
        for (int n = 0; n < 4; ++n) {
            const int o = n * 16 + ln;
            bfr[n] = *(const s8v*)((const char*)wt_lds +
                      (((o << 8) + (ks << 6) + (hi << 4)) ^ ((o & 7) << 4)));
        }

        if (ks < 2) {
            // AP half: h = ks*32 + 8hi + e
            const int h0 = ks * 32 + 8 * hi;
            float tif[8];
            {
                const s8v ti = *(const s8v*)((const char*)t_lds +
                               (((i << 7) + (h0 << 1)) ^ ((i & 7) << 4)));
#pragma unroll
                for (int e = 0; e < 8; ++e)
                    tif[e] = bf2f((unsigned short)ti[e]) + bAP_lds[h0 + e];
            }
#pragma unroll
            for (int m = 0; m < 2; ++m) {
                const int jm = (m == 0) ? j0 : j1;
                const s8v tj = *(const s8v*)((const char*)t_lds +
                               (((jm << 7) + (h0 << 1)) ^ ((jm & 7) << 4)));
                ABfrag af;
#pragma unroll
                for (int e = 0; e < 8; ++e) {
                    float v = fmaxf(tif[e] + bf2f((unsigned short)tj[e]), 0.f);
                    af.u[e] = (h0 + e < NH) ? f2bf(v) : 0;
                }
#pragma unroll
                for (int n = 0; n < 4; ++n)
                    acc[m][n] = __builtin_amdgcn_mfma_f32_16x16x32_bf16(af.v, bfr[n], acc[m][n], 0, 0, 0);
            }
        } else {
            // PP half: h = (ks-2)*32 + 8hi + e
            const int h0 = (ks - 2) * 32 + 8 * hi;
            float pa0[8], pa1[8];
#pragma unroll
            for (int e = 0; e < 8; ++e) { pa0[e] = bPP_lds[h0 + e]; pa1[e] = pa0[e]; }
#pragma unroll
            for (int f = 0; f < NPI; ++f) {
                const float4 wlo = *(const float4*)&wpp_lds[f * 64 + h0];
                const float4 whi = *(const float4*)&wpp_lds[f * 64 + h0 + 4];
                const float w8[8] = {wlo.x, wlo.y, wlo.z, wlo.w, whi.x, whi.y, whi.z, whi.w};
#pragma unroll
                for (int e = 0; e < 8; ++e) {
                    pa0[e] = fmaf(pr0[f], w8[e], pa0[e]);
                    pa1[e] = fmaf(pr1[f], w8[e], pa1[e]);
                }
            }
#pragma unroll
            for (int m = 0; m < 2; ++m) {
                float* pa = (m == 0) ? pa0 : pa1;
                ABfrag af;
#pragma unroll
                for (int e = 0; e < 8; ++e) {
                    float v = fmaxf(pa[e], 0.f);
                    af.u[e] = (h0 + e < NH) ? f2bf(v) : 0;
                }
#pragma unroll
                for (int n = 0; n < 4; ++n)
                    acc[m][n] = __builtin_amdgcn_mfma_f32_16x16x32_bf16(af.v, bfr[n], acc[m][n], 0, 0, 0);
            }
        }
    }

    // ---------------- epilogue: P stores ----------------
#pragma unroll
    for (int m = 0; m < 2; ++m) {
#pragma unroll
        for (int r = 0; r < 4; ++r) {
            const int row = wave * 32 + m * 16 + 4 * hi + r;
            const float pm = pm_lds[row];
            const size_t base = ((size_t)blockIdx.x * NM + row) * NPO;
#pragma unroll
            for (int n = 0; n < 4; ++n) {
                const int col = n * 16 + ln;
                float v = acc[m][n][r] + bP_lds[col];
                v = fmaxf(v, 0.f) * pm;
                if (col < NPO) outP[base + col] = v;
            }
        }
    }

    // ---------------- S_pair reduction in registers ----------------
    {
        float s2[NPI];
#pragma unroll
        for (int f = 0; f < NPI; ++f) s2[f] = pr0[f] + pr1[f];
#pragma unroll
        for (int f = 0; f < NPI; ++f) {
#pragma unroll
            for (int s = 1; s <= 8; s <<= 1) s2[f] += __shfl_xor(s2[f], s, 64);
        }
        if (lane == 0) {
#pragma unroll
            for (int f = 0; f < NPI; ++f) wred[wave][f] = s2[f];
        }
    }
    __syncthreads();
    if (tid < NPI) S_lds[tid] = wred[0][tid] + wred[1][tid] + wred[2][tid] + wred[3][tid];
    __syncthreads();
    if (tid < NH) {
        float aa = b_AA[tid];
#pragma unroll
        for (int f = 0; f < NAI; ++f) aa = fmaf(atom_lds[f], W_AA[f * NH + tid], aa);
        float pa = 128.f * b_PA[tid];
#pragma unroll
        for (int f = 0; f < NPI; ++f) pa = fmaf(S_lds[f], W_PA[f * NH + tid], pa);
        conc[tid]      = fmaxf(aa, 0.f);
        conc[NH + tid] = fmaxf(pa, 0.f);
    }
    __syncthreads();
    if (tid < NAO) {
        float a = b_A[tid];
#pragma unroll
        for (int hh = 0; hh < 2 * NH; ++hh) a = fmaf(conc[hh], W_A[hh * NAO + tid], a);
        outA[(size_t)blockIdx.x * NAO + tid] = fmaxf(a, 0.f) * amask[blockIdx.x];
    }
}

extern "C" void kernel_launch(void* const* d_in, const int* in_sizes, int n_in,
                              void* d_out, int out_size, void* d_ws, size_t ws_size,
                              hipStream_t stream) {
    const float* atom  = (const float*)d_in[0];
    const float* pairf = (const float*)d_in[1];
    const float* amask = (const float*)d_in[2];
    const float* pmask = (const float*)d_in[3];
    const float* W_AA  = (const float*)d_in[4];
    const float* b_AA  = (const float*)d_in[5];
    const float* W_PA  = (const float*)d_in[6];
    const float* b_PA  = (const float*)d_in[7];
    const float* W_A   = (const float*)d_in[8];
    const float* b_A   = (const float*)d_in[9];
    const float* W_AP  = (const float*)d_in[10];
    const float* b_AP  = (const float*)d_in[11];
    const float* W_PP  = (const float*)d_in[12];
    const float* b_PP  = (const float*)d_in[13];
    const float* W_P   = (const float*)d_in[14];
    const float* b_P   = (const float*)d_in[15];

    unsigned short* t_ws  = (unsigned short*)d_ws;                                     // 8192*64 bf16 = 1 MB
    unsigned short* wt_ws = (unsigned short*)((char*)d_ws + (size_t)NB * NM * 64 * 2); // 16 KB

    float* outA = (float*)d_out;
    float* outP = (float*)d_out + (size_t)NB * NM * NAO;

    k_t<<<(NB * NM * 64 + 255) / 256, 256, 0, stream>>>(atom, W_AP, t_ws);
    k_prep<<<(64 * 128 + 255) / 256, 256, 0, stream>>>(W_P, wt_ws);

    k_main<<<NB * NM, 256, 0, stream>>>(
        atom, pairf, amask, pmask,
        W_AA, b_AA, W_PA, b_PA, W_A, b_A, b_AP,
        W_PP, b_PP, b_P, t_ws, wt_ws, outA, outP);
}